// Round 8
// baseline (375.120 us; speedup 1.0000x reference)
//
#include <hip/hip_runtime.h>
#include <hip/hip_bf16.h>
#include <stdint.h>

#define N_NODES  50000
#define N_GRAPHS 256
#define DIM      128
#define N_EDGES  800000
#define K2       256            // fused K = [agg | h]
#define N_STRIPS (N_NODES / 16) // 3125, exact
#define PAD_CAP  64             // max degree slack (mean 16; fixed edge list, no overflow)
#define NBUCKET  196            // ceil(50000/256) buckets of 256 nodes (bucket = dst>>8)
#define NCHUNK   256            // edge chunks
#define CHUNK    3125           // NCHUNK*CHUNK == N_EDGES exactly
#define SROW     136            // LDS agg row stride in ushorts: 272B = 16B-aligned, 68 dwords -> 2-way banks

typedef __attribute__((ext_vector_type(8))) short  short8;
typedef __attribute__((ext_vector_type(4))) float  floatx4;

__device__ __forceinline__ ushort f2bf(float f) {
    union { float f; uint32_t u; } c; c.f = f;
    uint32_t u = c.u;
    return (ushort)((u + 0x7fffu + ((u >> 16) & 1u)) >> 16);  // RNE
}
__device__ __forceinline__ float bf2f(ushort b) {
    union { uint32_t u; float f; } c; c.u = ((uint32_t)b) << 16;
    return c.f;
}
__device__ __forceinline__ float bflo(uint32_t d) {   // low bf16 -> f32 (1 shl)
    union { uint32_t u; float f; } c; c.u = d << 16; return c.f;
}
__device__ __forceinline__ float bfhi(uint32_t d) {   // high bf16 -> f32 (1 and)
    union { uint32_t u; float f; } c; c.u = d & 0xffff0000u; return c.f;
}

// ---------- prep: fp32 x -> bf16 ----------
__global__ __launch_bounds__(256) void k_convert_x(const float* __restrict__ x,
                                                   ushort* __restrict__ xb) {
    int i = blockIdx.x * 256 + threadIdx.x;          // float4 index
    const int n4 = N_NODES * DIM / 4;
    if (i < n4) {
        float4 v = ((const float4*)x)[i];
        uint32_t lo = (uint32_t)f2bf(v.x) | ((uint32_t)f2bf(v.y) << 16);
        uint32_t hi = (uint32_t)f2bf(v.z) | ((uint32_t)f2bf(v.w) << 16);
        ((uint2*)xb)[i] = make_uint2(lo, hi);
    }
}

// ---------- prep: all 3 layers' Wt[n][k] = bf16( k<128 ? Wl[k][n] : Wr[k-128][n] ) ----------
__global__ __launch_bounds__(256) void k_prep_w_all(const float* __restrict__ Wl0, const float* __restrict__ Wr0,
                                                    const float* __restrict__ Wl1, const float* __restrict__ Wr1,
                                                    const float* __restrict__ Wl2, const float* __restrict__ Wr2,
                                                    ushort* __restrict__ Wt) {   // 3 * DIM * K2
    int i = blockIdx.x * 256 + threadIdx.x;
    if (i < 3 * DIM * K2) {
        int layer = i / (DIM * K2);
        int j = i % (DIM * K2);
        int n = j / K2, k = j % K2;
        const float* Wl = (layer == 0) ? Wl0 : (layer == 1) ? Wl1 : Wl2;
        const float* Wr = (layer == 0) ? Wr0 : (layer == 1) ? Wr1 : Wr2;
        float v = (k < DIM) ? Wl[k * DIM + n] : Wr[(k - DIM) * DIM + n];
        Wt[i] = f2bf(v);
    }
}

// ---------- radix bucket build (no global atomics) ----------
__global__ __launch_bounds__(256) void k_hist(const int* __restrict__ dst,
                                              int* __restrict__ counts) {  // [NCHUNK][NBUCKET]
    __shared__ int hist[NBUCKET];
    int t = threadIdx.x, b = blockIdx.x;
    if (t < NBUCKET) hist[t] = 0;
    __syncthreads();
    const int e0 = b * CHUNK;
    for (int i = t; i < CHUNK; i += 256)
        atomicAdd(&hist[dst[e0 + i] >> 8], 1);
    __syncthreads();
    if (t < NBUCKET) counts[b * NBUCKET + t] = hist[t];
}

__global__ __launch_bounds__(256) void k_scan_col(const int* __restrict__ counts,
                                                  int* __restrict__ off,     // [NCHUNK][NBUCKET]
                                                  int* __restrict__ total) { // [NBUCKET]
    __shared__ int buf[256];
    int t = threadIdx.x, j = blockIdx.x;            // j < NBUCKET
    int v = counts[t * NBUCKET + j];
    buf[t] = v;
    __syncthreads();
    #pragma unroll
    for (int d = 1; d < 256; d <<= 1) {
        int x = (t >= d) ? buf[t - d] : 0;
        __syncthreads();
        buf[t] += x;
        __syncthreads();
    }
    off[t * NBUCKET + j] = buf[t] - v;              // exclusive within column
    if (t == 255) total[j] = buf[255];
}

__global__ __launch_bounds__(256) void k_scan_total(const int* __restrict__ total,
                                                    int* __restrict__ basep) {
    __shared__ int buf[256];
    int t = threadIdx.x;
    int v = (t < NBUCKET) ? total[t] : 0;
    buf[t] = v;
    __syncthreads();
    #pragma unroll
    for (int d = 1; d < 256; d <<= 1) {
        int x = (t >= d) ? buf[t - d] : 0;
        __syncthreads();
        buf[t] += x;
        __syncthreads();
    }
    if (t < NBUCKET) basep[t] = buf[t] - v;         // exclusive
}

__global__ __launch_bounds__(256) void k_scatter(const int* __restrict__ src,
                                                 const int* __restrict__ dst,
                                                 const int* __restrict__ off,
                                                 const int* __restrict__ basep,
                                                 uint32_t* __restrict__ ebuf) {
    __shared__ int cur[NBUCKET];
    int t = threadIdx.x, b = blockIdx.x;
    if (t < NBUCKET) cur[t] = off[b * NBUCKET + t] + basep[t];
    __syncthreads();
    const int e0 = b * CHUNK;
    for (int i = t; i < CHUNK; i += 256) {
        int d = dst[e0 + i];
        int s = src[e0 + i];                         // < 50000 < 2^16
        int p = atomicAdd(&cur[d >> 8], 1);
        ebuf[p] = ((uint32_t)(d & 255) << 16) | (uint32_t)s;
    }
}

__global__ __launch_bounds__(256) void k_build(const uint32_t* __restrict__ ebuf,
                                               const int* __restrict__ total,
                                               const int* __restrict__ basep,
                                               int* __restrict__ padded,
                                               int* __restrict__ cnt) {
    __shared__ int lcnt[256];
    int t = threadIdx.x, j = blockIdx.x;
    lcnt[t] = 0;
    __syncthreads();
    int b0 = basep[j], tot = total[j];
    for (int i = t; i < tot; i += 256) {
        uint32_t v = ebuf[b0 + i];
        int dl = (int)(v >> 16);
        int s  = (int)(v & 0xffffu);
        int p  = atomicAdd(&lcnt[dl], 1);
        if (p < PAD_CAP) padded[((size_t)j * 256 + dl) * PAD_CAP + p] = s;
    }
    __syncthreads();
    int node = j * 256 + t;
    if (node < N_NODES) cnt[node] = lcnt[t];
}

// ---------- canonicalize adjacency: bitonic sort each node's list across one wave ----------
// Multiset per node is deterministic; sorting makes the summation order (and bf16
// rounding) a deterministic function of the edge set, independent of build order.
__global__ __launch_bounds__(256) void k_sort_adj(int* __restrict__ padded,
                                                  const int* __restrict__ cnt) {
    int wid  = threadIdx.x >> 6;
    int lane = threadIdx.x & 63;
    int node = blockIdx.x * 4 + wid;
    if (node >= N_NODES) return;
    int deg = cnt[node];
    int m   = deg < PAD_CAP ? deg : PAD_CAP;
    int* lst = padded + (size_t)node * PAD_CAP;
    int v = (lane < m) ? lst[lane] : 0x7fffffff;   // pad sorts to the end
    #pragma unroll
    for (int k = 2; k <= 64; k <<= 1) {
        #pragma unroll
        for (int j = k >> 1; j > 0; j >>= 1) {
            int other  = __shfl_xor(v, j, 64);
            bool down  = (lane & k) != 0;
            bool lower = (lane & j) == 0;
            v = (lower ^ down) ? min(v, other) : max(v, other);
        }
    }
    if (lane < m) lst[lane] = v;                   // ascending neighbor ids
}

// ---------- per-graph node ranges from sorted batch (no atomics) ----------
__global__ __launch_bounds__(256) void k_gbounds(const int* __restrict__ batch,
                                                 int* __restrict__ gstart,
                                                 int* __restrict__ gend) {
    int i = blockIdx.x * 256 + threadIdx.x;
    if (i >= N_NODES) return;
    int g = batch[i];
    if (i == 0) gstart[g] = 0;
    int gn = (i + 1 < N_NODES) ? batch[i + 1] : -1;
    if (gn != g) {
        gend[g] = i + 1;
        if (gn >= 0) gstart[gn] = i + 1;
    }
}

// ---------- fused SAGE layer v2: 1024-thread block, one wave per node ----------
// Phase 1: wave w gathers node r0+w. 16 lanes cover a 256B row (dwordx4), so a
// wave processes 4 edges per load inst, ILP 4 (16 edges in flight). Neighbor ids
// via one lst[lane] load + ds_bpermute. Cross-group combine: 2 shfl_xor rounds.
// Phase 2: waves 0..7 each compute one 16-col tile via MFMA.
template <bool OUT_F32>
__global__ __launch_bounds__(1024) void k_layer(const ushort* __restrict__ h_in,
                                                const int* __restrict__ padded,
                                                const int* __restrict__ cnt,
                                                const ushort* __restrict__ Wt,
                                                const float* __restrict__ bias,
                                                ushort* __restrict__ out_bf,
                                                float* __restrict__ out_f) {
    __shared__ ushort sAgg[16 * SROW];            // 4.25 KB, padded rows
    int wid  = threadIdx.x >> 6;                  // 0..15 = node slot
    int lane = threadIdx.x & 63;
    int r0   = blockIdx.x * 16;
    int node = r0 + wid;
    int deg  = cnt[node];
    int m    = deg < PAD_CAP ? deg : PAD_CAP;
    const int* lst = padded + (size_t)node * PAD_CAP;
    int vidx = lst[lane];                         // whole padded list in lanes (garbage past m never selected)
    int g    = lane >> 4;                         // edge group 0..3
    int l4   = lane & 15;                         // 16B slot within row
    const char* hbase = (const char*)h_in;

    float acc[8] = {0.f,0.f,0.f,0.f,0.f,0.f,0.f,0.f};
    for (int base = 0; base < m; base += 16) {
        uint4 v[4];
        #pragma unroll
        for (int s = 0; s < 4; ++s) {
            int e  = base + s * 4 + g;
            int ec = e < m ? e : m - 1;           // loop guard ensures m>0
            int nb = __builtin_amdgcn_ds_bpermute(ec << 2, vidx);
            v[s] = *(const uint4*)(hbase + ((size_t)(uint32_t)nb << 8) + (l4 << 4));
        }
        #pragma unroll
        for (int s = 0; s < 4; ++s) {
            int e = base + s * 4 + g;
            uint32_t d0 = (e < m) ? v[s].x : 0u;
            uint32_t d1 = (e < m) ? v[s].y : 0u;
            uint32_t d2 = (e < m) ? v[s].z : 0u;
            uint32_t d3 = (e < m) ? v[s].w : 0u;
            acc[0] += bflo(d0); acc[1] += bfhi(d0);
            acc[2] += bflo(d1); acc[3] += bfhi(d1);
            acc[4] += bflo(d2); acc[5] += bfhi(d2);
            acc[6] += bflo(d3); acc[7] += bfhi(d3);
        }
    }
    #pragma unroll
    for (int j = 0; j < 8; ++j) {                 // combine the 4 edge groups
        acc[j] += __shfl_xor(acc[j], 16, 64);
        acc[j] += __shfl_xor(acc[j], 32, 64);
    }
    if (lane < 16) {
        float inv = 1.0f / (float)(deg > 0 ? deg : 1);
        uint32_t w0 = (uint32_t)f2bf(acc[0]*inv) | ((uint32_t)f2bf(acc[1]*inv) << 16);
        uint32_t w1 = (uint32_t)f2bf(acc[2]*inv) | ((uint32_t)f2bf(acc[3]*inv) << 16);
        uint32_t w2 = (uint32_t)f2bf(acc[4]*inv) | ((uint32_t)f2bf(acc[5]*inv) << 16);
        uint32_t w3 = (uint32_t)f2bf(acc[6]*inv) | ((uint32_t)f2bf(acc[7]*inv) << 16);
        *(uint4*)((char*)sAgg + wid * (SROW * 2) + lane * 16) = make_uint4(w0, w1, w2, w3);
    }
    __syncthreads();

    // ---- phase 2: MFMA (waves 0..7, one col-tile each) ----
    if (wid < 8) {
        int row  = lane & 15;
        int quad = lane >> 4;
        short8 a[8];
        const ushort* srow = sAgg + row * SROW + quad * 8;
        #pragma unroll
        for (int ks = 0; ks < 4; ++ks) a[ks] = *(const short8*)(srow + ks * 32);  // ds_read_b128, 2-way banks
        const ushort* hrow = h_in + (size_t)(r0 + row) * DIM + quad * 8;
        #pragma unroll
        for (int ks = 0; ks < 4; ++ks) a[4 + ks] = *(const short8*)(hrow + ks * 32);

        int col = wid * 16 + row;
        const ushort* wrow = Wt + (size_t)col * K2 + quad * 8;
        floatx4 acc2 = {0.f, 0.f, 0.f, 0.f};
        #pragma unroll
        for (int ks = 0; ks < 8; ++ks) {
            short8 b = *(const short8*)(wrow + ks * 32);
            acc2 = __builtin_amdgcn_mfma_f32_16x16x32_bf16(a[ks], b, acc2, 0, 0, 0);
        }
        float bv = bias[col];
        #pragma unroll
        for (int r = 0; r < 4; ++r) {
            int mr = r0 + quad * 4 + r;           // C/D: col=lane&15, row=quad*4+reg
            float v = acc2[r] + bv;
            v = v > 0.f ? v : 0.f;
            if (OUT_F32) out_f[(size_t)mr * DIM + col] = v;
            else         out_bf[(size_t)mr * DIM + col] = f2bf(v);
        }
    }
}

// ---------- mean/max readout (batch sorted -> run-length flush) ----------
__global__ __launch_bounds__(128) void k_readout(const float* __restrict__ h,
                                                 const int* __restrict__ batch,
                                                 float* __restrict__ out) {
    int d  = threadIdx.x;                 // 0..127
    int n0 = blockIdx.x * 128;
    int n1 = min(n0 + 128, N_NODES);
    int cur = -1; float sum = 0.f, mx = 0.f;
    for (int i = n0; i < n1; ++i) {
        int g = batch[i];                 // block-uniform
        if (g != cur) {
            if (cur >= 0) {
                atomicAdd(&out[cur * 2 * DIM + d], sum);
                atomicMax((int*)&out[cur * 2 * DIM + DIM + d], __float_as_int(mx));
            }
            cur = g; sum = 0.f; mx = 0.f;
        }
        float v = h[(size_t)i * DIM + d];
        sum += v; mx = fmaxf(mx, v);
    }
    if (cur >= 0) {
        atomicAdd(&out[cur * 2 * DIM + d], sum);
        atomicMax((int*)&out[cur * 2 * DIM + DIM + d], __float_as_int(mx));
    }
}

__global__ __launch_bounds__(256) void k_finalize(float* __restrict__ out,
                                                  const int* __restrict__ gstart,
                                                  const int* __restrict__ gend) {
    int i = blockIdx.x * 256 + threadIdx.x;
    if (i < N_GRAPHS * DIM) {
        int g = i / DIM, d = i % DIM;
        int c = gend[g] - gstart[g];
        out[g * 2 * DIM + d] /= (float)(c > 0 ? c : 1);
    }
}

extern "C" void kernel_launch(void* const* d_in, const int* in_sizes, int n_in,
                              void* d_out, int out_size, void* d_ws, size_t ws_size,
                              hipStream_t stream) {
    const float* x     = (const float*)d_in[0];
    const int*   ei    = (const int*)d_in[1];
    const int*   src   = ei;
    const int*   dst   = ei + N_EDGES;
    const int*   batch = (const int*)d_in[2];
    const float* Wl[3] = {(const float*)d_in[3], (const float*)d_in[6], (const float*)d_in[9]};
    const float* bl[3] = {(const float*)d_in[4], (const float*)d_in[7], (const float*)d_in[10]};
    const float* Wr[3] = {(const float*)d_in[5], (const float*)d_in[8], (const float*)d_in[11]};
    float* out = (float*)d_out;

    char* base = (char*)d_ws;
    size_t o = 0;
    auto alloc = [&](size_t b) -> char* {
        char* p = base + o;
        o = (o + b + 255) & ~(size_t)255;
        return p;
    };
    int*     gstart = (int*)alloc((size_t)N_GRAPHS * 4);
    int*     gend   = (int*)alloc((size_t)N_GRAPHS * 4);
    size_t   zero_bytes = o;                      // gstart+gend contiguous
    int*     cnt    = (int*)alloc((size_t)N_NODES * 4);
    int*     counts = (int*)alloc((size_t)NCHUNK * NBUCKET * 4);
    int*     offs   = (int*)alloc((size_t)NCHUNK * NBUCKET * 4);
    int*     total  = (int*)alloc((size_t)NBUCKET * 4);
    int*     basep  = (int*)alloc((size_t)NBUCKET * 4);
    uint32_t* ebuf  = (uint32_t*)alloc((size_t)N_EDGES * 4);
    int*     padded = (int*)alloc((size_t)N_NODES * PAD_CAP * 4);    // 12.8 MB
    ushort*  xb     = (ushort*)alloc((size_t)N_NODES * DIM * 2);
    ushort*  ha     = (ushort*)alloc((size_t)N_NODES * DIM * 2);
    ushort*  hb     = (ushort*)alloc((size_t)N_NODES * DIM * 2);
    float*   h3     = (float*)alloc((size_t)N_NODES * DIM * 4);
    ushort*  Wt     = (ushort*)alloc((size_t)3 * DIM * K2 * 2);
    (void)ws_size; (void)n_in; (void)in_sizes;

    hipMemsetAsync(base, 0, zero_bytes, stream);
    hipMemsetAsync(d_out, 0, (size_t)out_size * 4, stream);

    k_convert_x<<<(N_NODES * DIM / 4 + 255) / 256, 256, 0, stream>>>(x, xb);
    k_prep_w_all<<<(3 * DIM * K2 + 255) / 256, 256, 0, stream>>>(
        Wl[0], Wr[0], Wl[1], Wr[1], Wl[2], Wr[2], Wt);

    k_hist<<<NCHUNK, 256, 0, stream>>>(dst, counts);
    k_scan_col<<<NBUCKET, 256, 0, stream>>>(counts, offs, total);
    k_scan_total<<<1, 256, 0, stream>>>(total, basep);
    k_scatter<<<NCHUNK, 256, 0, stream>>>(src, dst, offs, basep, ebuf);
    k_build<<<NBUCKET, 256, 0, stream>>>(ebuf, total, basep, padded, cnt);
    k_sort_adj<<<(N_NODES + 3) / 4, 256, 0, stream>>>(padded, cnt);
    k_gbounds<<<(N_NODES + 255) / 256, 256, 0, stream>>>(batch, gstart, gend);

    // fused layers (one kernel each)
    k_layer<false><<<N_STRIPS, 1024, 0, stream>>>(xb, padded, cnt, Wt,                bl[0], ha, nullptr);
    k_layer<false><<<N_STRIPS, 1024, 0, stream>>>(ha, padded, cnt, Wt + DIM * K2,     bl[1], hb, nullptr);
    k_layer<true ><<<N_STRIPS, 1024, 0, stream>>>(hb, padded, cnt, Wt + 2 * DIM * K2, bl[2], nullptr, h3);

    k_readout<<<(N_NODES + 127) / 128, 128, 0, stream>>>(h3, batch, out);
    k_finalize<<<(N_GRAPHS * DIM + 255) / 256, 256, 0, stream>>>(out, gstart, gend);
}